// Round 2
// baseline (24526.379 us; speedup 1.0000x reference)
//
#include <hip/hip_runtime.h>
#include <hip/hip_bf16.h>
#include <cstdint>
#include <cstddef>

// Encoder: x[32,128] -> embed(E) -> biGRU(fw,bw) -> concat -> GRU m0 -> m1 -> top
// Outputs: y_top [32,128,512], hT [32,512], concatenated flat in d_out
// (bf16 or f32 -- auto-detected on device).
//
// Round 2: device-side dtype probe. flags[0]=1 if float inputs are f32 (else
// bf16); flags[1]=1 if token ids are int64 (else int32). All kernels branch
// wave-uniformly on the flags. Intermediates are f32 in ws.
// ws regions (floats): A[0,6291456) B[6291456,12582912) C[12582912,16777216)
// flags at float offset 16777216 (2 ints). Total 67,108,872 bytes.
// Stage reuse: fwXP->A bwXP->B | biGRU->C | m0XP->B y1->A | m1XP->B y2->C |
// topXP->A | top gru -> d_out.

typedef __hip_bfloat16 bf16;

#define T_SEQ 128
#define NB    32
#define UNITS 512
#define THREE_U 1536

__device__ __forceinline__ float sigf(float v) {
    return 1.0f / (1.0f + __expf(-v));
}

__global__ void detect_dtypes(const void* __restrict__ Uprobe,
                              const void* __restrict__ xprobe,
                              int* __restrict__ flags)
{
    if (threadIdx.x == 0) {
        // U_fw glorot: |v| <= 0.054 -> bf16 exponent field < 128 always.
        // If the buffer is f32, even 16-bit halves are random mantissa bits:
        // ~half have exponent >= 128.
        const uint16_t* ub = (const uint16_t*)Uprobe;
        int big = 0;
        for (int i = 0; i < 64; ++i) {
            int e = (ub[i] >> 7) & 0xff;
            if (e >= 128) ++big;
        }
        flags[0] = (big >= 4) ? 1 : 0;
        // tokens < 2^31: if int64, every odd int32 word is 0.
        const int* xi = (const int*)xprobe;
        int nzodd = 0;
        for (int i = 1; i < 256; i += 2) if (xi[i] != 0) ++nzodd;
        flags[1] = (nzodd < 4) ? 1 : 0;
    }
}

__device__ __forceinline__ int tok_at(const void* x, int idx, bool i64) {
    return i64 ? (int)((const long long*)x)[idx] : ((const int*)x)[idx];
}

// C[4096,1536] = A[4096,K] @ W[K,1536] + b_in (row 0 of b).
// A from f32 ws buffer, or gathered rows E[tok] when xv != null.
// blockIdx.z selects parameter set 0/1 (fw/bw in one launch).
__global__ __launch_bounds__(256) void gemm_xp(
    const float* __restrict__ A, const void* __restrict__ xv,
    const void* __restrict__ E,
    const void* __restrict__ W0, const void* __restrict__ b0, float* __restrict__ C0,
    const void* __restrict__ W1, const void* __restrict__ b1, float* __restrict__ C1,
    int K, const int* __restrict__ flags)
{
    const bool f32w = flags[0] != 0;
    const bool i64 = flags[1] != 0;
    const void* W = W0; const void* bias = b0; float* C = C0;
    if (blockIdx.z == 1) { W = W1; bias = b1; C = C1; }

    __shared__ float As[32][68];   // [k][m]
    __shared__ float Ws[32][68];   // [k][n]

    const int tid = threadIdx.x;
    const int bn = blockIdx.x * 64;
    const int bm = blockIdx.y * 64;
    const int tx = tid & 15;
    const int ty = tid >> 4;

    float acc[4][4] = {};

    for (int k0 = 0; k0 < K; k0 += 32) {
#pragma unroll
        for (int i = 0; i < 8; ++i) {
            int idx = tid + i * 256;
            int kk = idx & 31;
            int mm = idx >> 5;
            int row = bm + mm;
            float v;
            if (xv) {
                size_t tok = (size_t)tok_at(xv, row, i64);
                size_t off = tok * (size_t)K + (k0 + kk);
                v = f32w ? ((const float*)E)[off]
                         : __bfloat162float(((const bf16*)E)[off]);
            } else {
                v = A[(size_t)row * K + (k0 + kk)];
            }
            As[kk][mm] = v;
        }
#pragma unroll
        for (int i = 0; i < 8; ++i) {
            int idx = tid + i * 256;
            int nn = idx & 63;
            int kk = idx >> 6;
            size_t off = (size_t)(k0 + kk) * THREE_U + (bn + nn);
            Ws[kk][nn] = f32w ? ((const float*)W)[off]
                              : __bfloat162float(((const bf16*)W)[off]);
        }
        __syncthreads();
#pragma unroll
        for (int k = 0; k < 32; ++k) {
            float a0 = As[k][ty*4+0], a1 = As[k][ty*4+1],
                  a2 = As[k][ty*4+2], a3 = As[k][ty*4+3];
            float w0 = Ws[k][tx*4+0], w1 = Ws[k][tx*4+1],
                  w2 = Ws[k][tx*4+2], w3 = Ws[k][tx*4+3];
            acc[0][0] += a0*w0; acc[0][1] += a0*w1; acc[0][2] += a0*w2; acc[0][3] += a0*w3;
            acc[1][0] += a1*w0; acc[1][1] += a1*w1; acc[1][2] += a1*w2; acc[1][3] += a1*w3;
            acc[2][0] += a2*w0; acc[2][1] += a2*w1; acc[2][2] += a2*w2; acc[2][3] += a2*w3;
            acc[3][0] += a3*w0; acc[3][1] += a3*w1; acc[3][2] += a3*w2; acc[3][3] += a3*w3;
        }
        __syncthreads();
    }

#pragma unroll
    for (int r = 0; r < 4; ++r) {
        float* Cp = C + (size_t)(bm + ty*4 + r) * THREE_U + bn;
#pragma unroll
        for (int c = 0; c < 4; ++c) {
            int bidx = bn + tx*4 + c;
            float bv = f32w ? ((const float*)bias)[bidx]
                            : __bfloat162float(((const bf16*)bias)[bidx]);
            Cp[tx*4 + c] = acc[r][c] + bv;
        }
    }
}

// One block (256 thr) per (batch, dir); thread j owns units 2j, 2j+1.
// bfull = BASE of b (2,3U); kernel uses row 1 (b_rec) at element THREE_U.
// If xp1 != null: blocks [32,64) are backward dir (reversed time), writing
// concat cols [512,1024) of y. If outv != null: top layer -- writes y (elems
// [0, 2097152)) and hT (elems [2097152, 2113536)) into d_out per dtype.
__global__ __launch_bounds__(256) void gru_rec(
    const float* __restrict__ xp0, const void* __restrict__ U0, const void* __restrict__ b0full,
    const float* __restrict__ xp1, const void* __restrict__ U1, const void* __restrict__ b1full,
    const void* __restrict__ x,
    float* __restrict__ y, int y_stride,
    void* __restrict__ outv,
    const int* __restrict__ flags)
{
    const bool f32w = flags[0] != 0;
    const bool i64 = flags[1] != 0;

    int blk = blockIdx.x;
    int b = blk;
    bool bwd = false;
    const float* xp = xp0; const void* U = U0; const void* bfull = b0full;
    int coloff = 0;
    if (xp1 != nullptr && blk >= NB) {
        b = blk - NB; bwd = true; xp = xp1; U = U1; bfull = b1full; coloff = UNITS;
    }

    __shared__ float h_s[UNITS];
    const int j = threadIdx.x;
    const int u0 = 2*j, u1 = u0 + 1;
    h_s[u0] = 0.f; h_s[u1] = 0.f;
    float h0 = 0.f, h1 = 0.f;

    // b_rec = element THREE_U onward of bfull: [z(512) r(512) h(512)]
    float bz0, bz1, brr0, brr1, bg0, bg1;
    if (f32w) {
        const float* bf = (const float*)bfull + THREE_U;
        bz0 = bf[u0]; bz1 = bf[u1];
        brr0 = bf[UNITS+u0]; brr1 = bf[UNITS+u1];
        bg0 = bf[2*UNITS+u0]; bg1 = bf[2*UNITS+u1];
    } else {
        const bf16* bb = (const bf16*)bfull + THREE_U;
        bz0 = __bfloat162float(bb[u0]); bz1 = __bfloat162float(bb[u1]);
        brr0 = __bfloat162float(bb[UNITS+u0]); brr1 = __bfloat162float(bb[UNITS+u1]);
        bg0 = __bfloat162float(bb[2*UNITS+u0]); bg1 = __bfloat162float(bb[2*UNITS+u1]);
    }

    __syncthreads();

    for (int ts = 0; ts < T_SEQ; ++ts) {
        const int t = bwd ? (T_SEQ - 1 - ts) : ts;
        const bool m = (tok_at(x, b * T_SEQ + t, i64) != 0);
        const float* xpt = xp + ((size_t)b * T_SEQ + t) * THREE_U;
        const float xz0 = xpt[u0],          xz1 = xpt[u1];
        const float xr0 = xpt[UNITS+u0],    xr1 = xpt[UNITS+u1];
        const float xh0 = xpt[2*UNITS+u0],  xh1 = xpt[2*UNITS+u1];

        float az0=0.f, az1=0.f, ar0=0.f, ar1=0.f, ag0=0.f, ag1=0.f;
        if (!f32w) {
            // bf16 U: row k = 768 uint32; pair j at uint32 col j; gates +256,+512
            const uint32_t* Uk = (const uint32_t*)U + j;
#pragma unroll 4
            for (int k = 0; k < UNITS; ++k) {
                const float hk = h_s[k];
                const uint32_t wz = Uk[0];
                const uint32_t wr = Uk[256];
                const uint32_t wg = Uk[512];
                az0 += hk * __uint_as_float(wz << 16);
                az1 += hk * __uint_as_float(wz & 0xffff0000u);
                ar0 += hk * __uint_as_float(wr << 16);
                ar1 += hk * __uint_as_float(wr & 0xffff0000u);
                ag0 += hk * __uint_as_float(wg << 16);
                ag1 += hk * __uint_as_float(wg & 0xffff0000u);
                Uk += 768;
            }
        } else {
            const float* Uk = (const float*)U + u0;
#pragma unroll 4
            for (int k = 0; k < UNITS; ++k) {
                const float hk = h_s[k];
                az0 += hk * Uk[0];
                az1 += hk * Uk[1];
                ar0 += hk * Uk[UNITS];
                ar1 += hk * Uk[UNITS+1];
                ag0 += hk * Uk[2*UNITS];
                ag1 += hk * Uk[2*UNITS+1];
                Uk += THREE_U;
            }
        }

        const float z0 = sigf(xz0 + az0 + bz0);
        const float z1 = sigf(xz1 + az1 + bz1);
        const float r0 = sigf(xr0 + ar0 + brr0);
        const float r1 = sigf(xr1 + ar1 + brr1);
        const float g0 = sigf(xh0 + r0 * (ag0 + bg0));
        const float g1 = sigf(xh1 + r1 * (ag1 + bg1));
        float hn0 = z0*h0 + (1.f - z0)*g0;
        float hn1 = z1*h1 + (1.f - z1)*g1;
        if (!m) { hn0 = h0; hn1 = h1; }
        h0 = hn0; h1 = hn1;

        __syncthreads();            // all dot-product reads of h_s done
        h_s[u0] = h0; h_s[u1] = h1;
        __syncthreads();            // new h visible

        if (outv) {
            const size_t o = ((size_t)b * T_SEQ + t) * UNITS;
            const size_t oh = (size_t)NB * T_SEQ * UNITS + (size_t)b * UNITS;
            if (f32w) {
                float* of = (float*)outv;
                of[o + u0] = hn0;
                of[o + u1] = hn1;
                if (ts == T_SEQ - 1) { of[oh + u0] = hn0; of[oh + u1] = hn1; }
            } else {
                bf16* ob = (bf16*)outv;
                ob[o + u0] = __float2bfloat16(hn0);
                ob[o + u1] = __float2bfloat16(hn1);
                if (ts == T_SEQ - 1) {
                    ob[oh + u0] = __float2bfloat16(hn0);
                    ob[oh + u1] = __float2bfloat16(hn1);
                }
            }
        } else {
            float* yp = y + ((size_t)b * T_SEQ + t) * y_stride + coloff;
            yp[u0] = hn0; yp[u1] = hn1;
        }
    }
}

extern "C" void kernel_launch(void* const* d_in, const int* in_sizes, int n_in,
                              void* d_out, int out_size, void* d_ws, size_t ws_size,
                              hipStream_t stream) {
    const void* x     = d_in[0];
    const void* E     = d_in[2];
    const void* W_fw  = d_in[3];
    const void* U_fw  = d_in[4];
    const void* b_fw  = d_in[5];
    const void* W_bw  = d_in[6];
    const void* U_bw  = d_in[7];
    const void* b_bw  = d_in[8];
    const void* W_m0  = d_in[9];
    const void* U_m0  = d_in[10];
    const void* b_m0  = d_in[11];
    const void* W_m1  = d_in[12];
    const void* U_m1  = d_in[13];
    const void* b_m1  = d_in[14];
    const void* W_top = d_in[15];
    const void* U_top = d_in[16];
    const void* b_top = d_in[17];

    float* ws = (float*)d_ws;
    float* A  = ws;                    // 6291456 floats
    float* B  = ws + 6291456;
    float* C  = ws + 12582912;         // 4194304 floats
    int* flags = (int*)(ws + 16777216);

    detect_dtypes<<<1, 64, 0, stream>>>(U_fw, x, flags);

    const dim3 blk(256);
    const dim3 g2(24, 64, 2);
    const dim3 g1(24, 64, 1);

    // fw & bw input projections (gathered embedding)
    gemm_xp<<<g2, blk, 0, stream>>>(nullptr, x, E,
                                    W_fw, b_fw, A,
                                    W_bw, b_bw, B, 512, flags);
    // biGRU -> concat C (stride 1024)
    gru_rec<<<64, blk, 0, stream>>>(A, U_fw, b_fw,
                                    B, U_bw, b_bw,
                                    x, C, 1024, nullptr, flags);
    // m0 (K=1024): reads C, xp->B, y1->A
    gemm_xp<<<g1, blk, 0, stream>>>(C, nullptr, nullptr,
                                    W_m0, b_m0, B,
                                    nullptr, nullptr, nullptr, 1024, flags);
    gru_rec<<<32, blk, 0, stream>>>(B, U_m0, b_m0,
                                    nullptr, nullptr, nullptr,
                                    x, A, 512, nullptr, flags);
    // m1: reads A(y1), xp->B, y2->C
    gemm_xp<<<g1, blk, 0, stream>>>(A, nullptr, nullptr,
                                    W_m1, b_m1, B,
                                    nullptr, nullptr, nullptr, 512, flags);
    gru_rec<<<32, blk, 0, stream>>>(B, U_m1, b_m1,
                                    nullptr, nullptr, nullptr,
                                    x, C, 512, nullptr, flags);
    // top: reads C(y2), xp->A, out->d_out
    gemm_xp<<<g1, blk, 0, stream>>>(C, nullptr, nullptr,
                                    W_top, b_top, A,
                                    nullptr, nullptr, nullptr, 512, flags);
    gru_rec<<<32, blk, 0, stream>>>(A, U_top, b_top,
                                    nullptr, nullptr, nullptr,
                                    x, nullptr, 0, d_out, flags);
}

// Round 3
// 6652.215 us; speedup vs baseline: 3.6869x; 3.6869x over previous
//
#include <hip/hip_runtime.h>
#include <hip/hip_bf16.h>
#include <cstdint>
#include <cstddef>

// Encoder: x[32,128] -> embed(E) -> biGRU(fw,bw) -> concat -> GRU m0 -> m1 -> top
// R3: weight-stationary recurrence. 16 blocks/group, 384 thr (6 waves); each
// wave holds its 512x16 U-slice as 16 MFMA B-frags in registers. h exchanged
// per step via global bf16 double buffer + device-scope counter sync.
// Master h state stays f32 in LDS (bf16 only enters matmul input).
//
// ws (floats): A[0,6291456) B[..12582912) C[..16777216)
//   flags @16777216 (2 int), counters @16777218 (8 u32), hbufs @16777232
//   (4 x 16384 bf16 = 32768 floats). Total ~64.13 MiB.

typedef __hip_bfloat16 bf16;
typedef __attribute__((ext_vector_type(8))) short short8;   // 8 bf16 (4 VGPRs)
typedef __attribute__((ext_vector_type(4))) float f32x4;

#define T_SEQ 128
#define NB    32
#define UNITS 512
#define THREE_U 1536
#define GBLKS 16

__device__ __forceinline__ float sigf(float v) {
    return 1.0f / (1.0f + __expf(-v));
}

__global__ void detect_dtypes(const void* __restrict__ Uprobe,
                              const void* __restrict__ xprobe,
                              int* __restrict__ flags)
{
    if (threadIdx.x == 0) {
        const uint16_t* ub = (const uint16_t*)Uprobe;
        int big = 0;
        for (int i = 0; i < 64; ++i) {
            int e = (ub[i] >> 7) & 0xff;
            if (e >= 128) ++big;
        }
        flags[0] = (big >= 4) ? 1 : 0;   // 1: floats are f32
        const int* xi = (const int*)xprobe;
        int nzodd = 0;
        for (int i = 1; i < 256; i += 2) if (xi[i] != 0) ++nzodd;
        flags[1] = (nzodd < 4) ? 1 : 0;  // 1: ints are int64
    }
}

__device__ __forceinline__ int tok_at(const void* x, int idx, bool i64) {
    return i64 ? (int)((const long long*)x)[idx] : ((const int*)x)[idx];
}

// ---------------- input-projection GEMM (unchanged from R2) ----------------
__global__ __launch_bounds__(256) void gemm_xp(
    const float* __restrict__ A, const void* __restrict__ xv,
    const void* __restrict__ E,
    const void* __restrict__ W0, const void* __restrict__ b0, float* __restrict__ C0,
    const void* __restrict__ W1, const void* __restrict__ b1, float* __restrict__ C1,
    int K, const int* __restrict__ flags)
{
    const bool f32w = flags[0] != 0;
    const bool i64 = flags[1] != 0;
    const void* W = W0; const void* bias = b0; float* C = C0;
    if (blockIdx.z == 1) { W = W1; bias = b1; C = C1; }

    __shared__ float As[32][68];
    __shared__ float Ws[32][68];

    const int tid = threadIdx.x;
    const int bn = blockIdx.x * 64;
    const int bm = blockIdx.y * 64;
    const int tx = tid & 15;
    const int ty = tid >> 4;

    float acc[4][4] = {};

    for (int k0 = 0; k0 < K; k0 += 32) {
#pragma unroll
        for (int i = 0; i < 8; ++i) {
            int idx = tid + i * 256;
            int kk = idx & 31;
            int mm = idx >> 5;
            int row = bm + mm;
            float v;
            if (xv) {
                size_t tok = (size_t)tok_at(xv, row, i64);
                size_t off = tok * (size_t)K + (k0 + kk);
                v = f32w ? ((const float*)E)[off]
                         : __bfloat162float(((const bf16*)E)[off]);
            } else {
                v = A[(size_t)row * K + (k0 + kk)];
            }
            As[kk][mm] = v;
        }
#pragma unroll
        for (int i = 0; i < 8; ++i) {
            int idx = tid + i * 256;
            int nn = idx & 63;
            int kk = idx >> 6;
            size_t off = (size_t)(k0 + kk) * THREE_U + (bn + nn);
            Ws[kk][nn] = f32w ? ((const float*)W)[off]
                              : __bfloat162float(((const bf16*)W)[off]);
        }
        __syncthreads();
#pragma unroll
        for (int k = 0; k < 32; ++k) {
            float a0 = As[k][ty*4+0], a1 = As[k][ty*4+1],
                  a2 = As[k][ty*4+2], a3 = As[k][ty*4+3];
            float w0 = Ws[k][tx*4+0], w1 = Ws[k][tx*4+1],
                  w2 = Ws[k][tx*4+2], w3 = Ws[k][tx*4+3];
            acc[0][0] += a0*w0; acc[0][1] += a0*w1; acc[0][2] += a0*w2; acc[0][3] += a0*w3;
            acc[1][0] += a1*w0; acc[1][1] += a1*w1; acc[1][2] += a1*w2; acc[1][3] += a1*w3;
            acc[2][0] += a2*w0; acc[2][1] += a2*w1; acc[2][2] += a2*w2; acc[2][3] += a2*w3;
            acc[3][0] += a3*w0; acc[3][1] += a3*w1; acc[3][2] += a3*w2; acc[3][3] += a3*w3;
        }
        __syncthreads();
    }

#pragma unroll
    for (int r = 0; r < 4; ++r) {
        float* Cp = C + (size_t)(bm + ty*4 + r) * THREE_U + bn;
#pragma unroll
        for (int c = 0; c < 4; ++c) {
            int bidx = bn + tx*4 + c;
            float bv = f32w ? ((const float*)bias)[bidx]
                            : __bfloat162float(((const bf16*)bias)[bidx]);
            Cp[tx*4 + c] = acc[r][c] + bv;
        }
    }
}

// ---------------- weight-stationary GRU recurrence ----------------
// Grid: GBLKS per group (x2 groups for biGRU). Block g owns units
// [g*32, g*32+32). Wave w (0..5): gate=w>>1 (z,r,hh), half=w&1; holds B-frags
// for its 16 cols x K=512. h exchange: bf16 [b][k] double buffer per group.
__global__ __launch_bounds__(384) void gru_mfma(
    const float* __restrict__ xp0, const void* __restrict__ U0, const void* __restrict__ b0full,
    const float* __restrict__ xp1, const void* __restrict__ U1, const void* __restrict__ b1full,
    const void* __restrict__ x,
    float* __restrict__ y, int y_stride,
    void* __restrict__ outv,
    uint16_t* __restrict__ hbase,
    unsigned* __restrict__ counters, int ctr_base,
    const int* __restrict__ flags)
{
    const bool f32w = flags[0] != 0;
    const bool i64  = flags[1] != 0;

    int group = 0, gblk = blockIdx.x;
    const float* xp = xp0; const void* U = U0; const void* bfull = b0full;
    bool bwd = false; int coloff = 0;
    if (xp1 != nullptr) {
        group = blockIdx.x >> 4; gblk = blockIdx.x & 15;
        if (group == 1) { bwd = true; xp = xp1; U = U1; bfull = b1full; coloff = UNITS; }
    }
    unsigned* cnt = counters + ctr_base + group;
    uint16_t* hpair = hbase + group * 2 * (NB*UNITS);

    const int tid  = threadIdx.x;
    const int wave = tid >> 6;
    const int lane = tid & 63;
    const int quad = lane >> 4;
    const int ncol = lane & 15;
    const int gate_w = wave >> 1;   // 0=z 1=r 2=hh
    const int hf     = wave & 1;    // unit half

    __shared__ float gatesLDS[3][NB][32];   // [gate][batch][unit_local]
    __shared__ float hsLDS[NB][32];         // master h (f32)
    __shared__ float biasLDS[3][32];

    for (int p = tid; p < NB*32; p += 384) hsLDS[p >> 5][p & 31] = 0.f;
    if (tid < 96) {
        int g = tid >> 5, u = tid & 31;
        int idx = THREE_U + g*UNITS + gblk*32 + u;   // b_rec row
        biasLDS[g][u] = f32w ? ((const float*)bfull)[idx]
                             : __bfloat162float(((const bf16*)bfull)[idx]);
    }

    // Register-resident B-frags: B[k][n], lane n=ncol, k = kk*32 + quad*8 + j
    short8 Bf[16];
    {
        const int col = gate_w*UNITS + gblk*32 + hf*16 + ncol;
#pragma unroll
        for (int kk = 0; kk < 16; ++kk) {
            short8 v;
#pragma unroll
            for (int j = 0; j < 8; ++j) {
                int k = kk*32 + quad*8 + j;
                unsigned short bits;
                if (f32w) {
                    bits = __builtin_bit_cast(unsigned short,
                        __float2bfloat16(((const float*)U)[(size_t)k*THREE_U + col]));
                } else {
                    bits = ((const uint16_t*)U)[(size_t)k*THREE_U + col];
                }
                v[j] = (short)bits;
            }
            Bf[kk] = v;
        }
    }
    __syncthreads();

    for (int ts = 0; ts < T_SEQ; ++ts) {
        const int t = bwd ? (T_SEQ-1-ts) : ts;
        const uint16_t* hc = hpair + (ts & 1) * (NB*UNITS);
        uint16_t* hnx      = hpair + ((ts+1) & 1) * (NB*UNITS);

        // rec = h[32,512] @ Uslice[512,16]; A-frag: lane m=ncol, k=quad*8+j
        f32x4 acc0 = {0.f,0.f,0.f,0.f};
        f32x4 acc1 = {0.f,0.f,0.f,0.f};
        {
            const uint16_t* base0 = hc + (size_t)ncol*UNITS + quad*8;      // batches 0..15
            const uint16_t* base1 = base0 + 16*UNITS;                       // batches 16..31
#pragma unroll
            for (int kk = 0; kk < 16; ++kk) {
                short8 a0 = *(const short8*)(base0 + kk*32);
                short8 a1 = *(const short8*)(base1 + kk*32);
                acc0 = __builtin_amdgcn_mfma_f32_16x16x32_bf16(a0, Bf[kk], acc0, 0, 0, 0);
                acc1 = __builtin_amdgcn_mfma_f32_16x16x32_bf16(a1, Bf[kk], acc1, 0, 0, 0);
            }
        }
        // C/D layout: col = lane&15 (our unit col), row = quad*4 + reg (batch)
        {
            const int u = hf*16 + ncol;
#pragma unroll
            for (int r = 0; r < 4; ++r) {
                gatesLDS[gate_w][quad*4 + r][u]      = acc0[r];
                gatesLDS[gate_w][16 + quad*4 + r][u] = acc1[r];
            }
        }
        __syncthreads();

        // gate epilogue: 1024 (b,u) pairs; each pair owned by one fixed thread
        for (int p = tid; p < NB*32; p += 384) {
            const int b = p >> 5, u = p & 31;
            const int ug = gblk*32 + u;
            const float hprev = hsLDS[b][u];
            const float* xpt = xp + ((size_t)b*T_SEQ + t) * THREE_U + ug;
            const float xz = xpt[0], xr = xpt[UNITS], xh = xpt[2*UNITS];
            const float rz = gatesLDS[0][b][u] + biasLDS[0][u];
            const float rr = gatesLDS[1][b][u] + biasLDS[1][u];
            const float rh = gatesLDS[2][b][u] + biasLDS[2][u];
            const float z = sigf(xz + rz);
            const float r = sigf(xr + rr);
            const float g = sigf(xh + r*rh);
            float hn = z*hprev + (1.f - z)*g;
            if (tok_at(x, b*T_SEQ + t, i64) == 0) hn = hprev;
            hsLDS[b][u] = hn;
            hnx[b*UNITS + ug] = __builtin_bit_cast(unsigned short, __float2bfloat16(hn));
            if (outv) {
                const size_t o = ((size_t)b*T_SEQ + t)*UNITS + ug;
                if (f32w) {
                    ((float*)outv)[o] = hn;
                    if (ts == T_SEQ-1)
                        ((float*)outv)[(size_t)NB*T_SEQ*UNITS + (size_t)b*UNITS + ug] = hn;
                } else {
                    ((bf16*)outv)[o] = __float2bfloat16(hn);
                    if (ts == T_SEQ-1)
                        ((bf16*)outv)[(size_t)NB*T_SEQ*UNITS + (size_t)b*UNITS + ug] = __float2bfloat16(hn);
                }
            } else {
                y[((size_t)b*T_SEQ + t)*y_stride + coloff + ug] = hn;
            }
        }
        __syncthreads();   // all h_next stores drained (barrier implies waitcnt)

        if (ts < T_SEQ-1) {
            if (tid == 0) {
                __threadfence();   // agent release: write back h_next
                __hip_atomic_fetch_add(cnt, 1u, __ATOMIC_RELEASE, __HIP_MEMORY_SCOPE_AGENT);
                const unsigned target = (unsigned)GBLKS * (unsigned)(ts + 1);
                while (__hip_atomic_load(cnt, __ATOMIC_ACQUIRE, __HIP_MEMORY_SCOPE_AGENT) < target) {
                    __builtin_amdgcn_s_sleep(2);
                }
                __threadfence();   // acquire: invalidate stale L1/L2 lines
            }
            __syncthreads();
        }
    }
}

extern "C" void kernel_launch(void* const* d_in, const int* in_sizes, int n_in,
                              void* d_out, int out_size, void* d_ws, size_t ws_size,
                              hipStream_t stream) {
    const void* x     = d_in[0];
    const void* E     = d_in[2];
    const void* W_fw  = d_in[3];
    const void* U_fw  = d_in[4];
    const void* b_fw  = d_in[5];
    const void* W_bw  = d_in[6];
    const void* U_bw  = d_in[7];
    const void* b_bw  = d_in[8];
    const void* W_m0  = d_in[9];
    const void* U_m0  = d_in[10];
    const void* b_m0  = d_in[11];
    const void* W_m1  = d_in[12];
    const void* U_m1  = d_in[13];
    const void* b_m1  = d_in[14];
    const void* W_top = d_in[15];
    const void* U_top = d_in[16];
    const void* b_top = d_in[17];

    float* ws = (float*)d_ws;
    float* A  = ws;                    // 6291456 floats
    float* B  = ws + 6291456;
    float* C  = ws + 12582912;         // 4194304 floats
    int* flags = (int*)(ws + 16777216);
    unsigned* ctrs = (unsigned*)(ws + 16777218);
    uint16_t* hb = (uint16_t*)(ws + 16777232);   // 4 x 16384 bf16

    // zero flags + counters + h buffers (ws is 0xAA-poisoned before each call)
    hipMemsetAsync((char*)d_ws + 16777216u*4u, 0, 64 + 4*2*NB*UNITS*2, stream);
    detect_dtypes<<<1, 64, 0, stream>>>(U_fw, x, flags);

    const dim3 blk(256);
    const dim3 g2(24, 64, 2);
    const dim3 g1(24, 64, 1);

    // fw & bw input projections (gathered embedding)
    gemm_xp<<<g2, blk, 0, stream>>>(nullptr, x, E,
                                    W_fw, b_fw, A,
                                    W_bw, b_bw, B, 512, flags);
    // biGRU -> concat C (stride 1024); groups fw(ctr0), bw(ctr1)
    gru_mfma<<<32, 384, 0, stream>>>(A, U_fw, b_fw,
                                     B, U_bw, b_bw,
                                     x, C, 1024, nullptr, hb, ctrs, 0, flags);
    // m0 (K=1024): C -> xp B, y1 -> A
    gemm_xp<<<g1, blk, 0, stream>>>(C, nullptr, nullptr,
                                    W_m0, b_m0, B,
                                    nullptr, nullptr, nullptr, 1024, flags);
    hipMemsetAsync(hb, 0, 2*NB*UNITS*2, stream);   // re-zero group-0 h pair
    gru_mfma<<<16, 384, 0, stream>>>(B, U_m0, b_m0,
                                     nullptr, nullptr, nullptr,
                                     x, A, 512, nullptr, hb, ctrs, 2, flags);
    // m1: A(y1) -> xp B, y2 -> C
    gemm_xp<<<g1, blk, 0, stream>>>(A, nullptr, nullptr,
                                    W_m1, b_m1, B,
                                    nullptr, nullptr, nullptr, 512, flags);
    hipMemsetAsync(hb, 0, 2*NB*UNITS*2, stream);
    gru_mfma<<<16, 384, 0, stream>>>(B, U_m1, b_m1,
                                     nullptr, nullptr, nullptr,
                                     x, C, 512, nullptr, hb, ctrs, 3, flags);
    // top: C(y2) -> xp A, out -> d_out
    gemm_xp<<<g1, blk, 0, stream>>>(C, nullptr, nullptr,
                                    W_top, b_top, A,
                                    nullptr, nullptr, nullptr, 512, flags);
    hipMemsetAsync(hb, 0, 2*NB*UNITS*2, stream);
    gru_mfma<<<16, 384, 0, stream>>>(A, U_top, b_top,
                                     nullptr, nullptr, nullptr,
                                     x, nullptr, 0, d_out, hb, ctrs, 4, flags);
}

// Round 6
// 4761.761 us; speedup vs baseline: 5.1507x; 1.3970x over previous
//
#include <hip/hip_runtime.h>
#include <hip/hip_bf16.h>
#include <cstdint>
#include <cstddef>

// Encoder: x[32,128] -> embed(E) -> biGRU(fw,bw) -> concat -> GRU m0 -> m1 -> top
// R6: fix R5's precision regression (absmax 0.037 from bf16 y intermediates).
// y intermediates back to f32; gemm_mfma uses split-bf16 A (hi+lo, 2 MFMAs)
// for f32-accurate products. h-exchange stays bf16 (R3-proven, 0.0039).
//
// ws layout (float offsets):
//   XPA 0..6291456         fw/moving xp (4096x1536 f32)
//   XPB 6291456..12582912  bw xp; later: Y1@+0 (2097152), Y2@+2097152,
//                          WTL@+4194304 (786432 f, m0/m1/top WT)
//   YBI 12582912..16777216 bi concat y f32 4096x1024; early WT (fw,bw) aliases
//                          here before gru-bi overwrites it
//   FLG 16777216 (2 int)  BAR 16777224 (128 int)  H 16777352 (32768 f)
//   END 16810120 f = 67.24 MB

typedef __hip_bfloat16 bf16;
typedef __attribute__((ext_vector_type(8))) short short8;   // 8 bf16
typedef __attribute__((ext_vector_type(4))) float f32x4;

#define T_SEQ 128
#define NB    32
#define UNITS 512
#define THREE_U 1536
#define GBLKS 16

#define OFF_XPA 0
#define OFF_XPB 6291456
#define OFF_YBI 12582912
#define OFF_FLG 16777216
#define OFF_BAR 16777224
#define OFF_H   16777352
#define OFF_END 16810120

__device__ __forceinline__ float sigf(float v) {
    return 1.0f / (1.0f + __expf(-v));
}

__global__ void detect_dtypes(const void* __restrict__ Uprobe,
                              const void* __restrict__ xprobe,
                              int* __restrict__ flags)
{
    if (threadIdx.x == 0) {
        const uint16_t* ub = (const uint16_t*)Uprobe;
        int big = 0;
        for (int i = 0; i < 64; ++i) {
            int e = (ub[i] >> 7) & 0xff;
            if (e >= 128) ++big;
        }
        flags[0] = (big >= 4) ? 1 : 0;   // 1: floats are f32
        const int* xi = (const int*)xprobe;
        int nzodd = 0;
        for (int i = 1; i < 256; i += 2) if (xi[i] != 0) ++nzodd;
        flags[1] = (nzodd < 4) ? 1 : 0;  // 1: ints are int64
    }
}

__device__ __forceinline__ int tok_at(const void* x, int idx, bool i64) {
    return i64 ? (int)((const long long*)x)[idx] : ((const int*)x)[idx];
}

// ---------------- W transpose: W[K][1536] -> WT[1536][K] bf16 ----------------
__global__ __launch_bounds__(256) void transpose_w(
    const void* __restrict__ W, uint16_t* __restrict__ WT, int K,
    const int* __restrict__ flags)
{
    const bool f32w = flags[0] != 0;
    __shared__ uint16_t tile[32][33];
    const int k0 = blockIdx.x * 32;
    const int n0 = blockIdx.y * 32;
    const int c = threadIdx.x & 31, r4 = threadIdx.x >> 5;
#pragma unroll
    for (int rr = 0; rr < 32; rr += 8) {
        int k = k0 + rr + r4;
        size_t off = (size_t)k * THREE_U + n0 + c;
        uint16_t v;
        if (f32w) v = __builtin_bit_cast(unsigned short, __float2bfloat16(((const float*)W)[off]));
        else      v = ((const uint16_t*)W)[off];
        tile[rr + r4][c] = v;
    }
    __syncthreads();
#pragma unroll
    for (int rr = 0; rr < 32; rr += 8) {
        int n = rr + r4;
        WT[(size_t)(n0 + n) * K + k0 + c] = tile[c][n];
    }
}

// ---------------- MFMA input-projection GEMM (split-bf16 A) ----------------
// C[4096][1536] f32 = A @ WT[n][k] + b_in. A element a is split hi+lo bf16;
// two MFMAs give ~f32 product accuracy. A from f32 buffer (lda) or E[tok]
// gather (bf16 rows -> lo = 0 automatically).
__global__ __launch_bounds__(256) void gemm_mfma(
    const float* __restrict__ Af, int lda,
    const void* __restrict__ xv, const void* __restrict__ E,
    const uint16_t* __restrict__ WT0, const void* __restrict__ b0, float* __restrict__ C0,
    const uint16_t* __restrict__ WT1, const void* __restrict__ b1, float* __restrict__ C1,
    int K, const int* __restrict__ flags)
{
    const bool f32w = flags[0] != 0;
    const bool i64  = flags[1] != 0;
    const uint16_t* WT = WT0; const void* bias = b0; float* C = C0;
    if (blockIdx.z == 1) { WT = WT1; bias = b1; C = C1; }

    __shared__ uint16_t AsHi[64][40];   // [m][k] stride 40
    __shared__ uint16_t AsLo[64][40];
    __shared__ uint16_t Ws[64][40];     // [n][k]

    const int tid = threadIdx.x;
    const int bn = blockIdx.x * 64, bm = blockIdx.y * 64;
    const int wave = tid >> 6, lane = tid & 63, quad = lane >> 4, l15 = lane & 15;
    const int wm = (wave & 1) * 32, wn = (wave >> 1) * 32;
    const int arow = tid >> 2;         // 0..63
    const int akoff = (tid & 3) * 8;   // 0,8,16,24

    f32x4 acc[2][2] = {};

    for (int k0 = 0; k0 < K; k0 += 32) {
        {
            const int mrow = bm + arow;
            float av[8];
            if (xv) {
                size_t tok = (size_t)tok_at(xv, mrow, i64);
                if (f32w) {
                    const float* p = (const float*)E + tok * (size_t)K + k0 + akoff;
#pragma unroll
                    for (int j = 0; j < 8; ++j) av[j] = p[j];
                } else {
                    const uint16_t* p = (const uint16_t*)E + tok * (size_t)K + k0 + akoff;
#pragma unroll
                    for (int j = 0; j < 8; ++j)
                        av[j] = __uint_as_float((unsigned)p[j] << 16);
                }
            } else {
                const float* p = Af + (size_t)mrow * lda + k0 + akoff;
#pragma unroll
                for (int j = 0; j < 8; ++j) av[j] = p[j];
            }
            short8 vh, vl;
#pragma unroll
            for (int j = 0; j < 8; ++j) {
                unsigned short hb = __builtin_bit_cast(unsigned short, __float2bfloat16(av[j]));
                float hi = __uint_as_float((unsigned)hb << 16);
                unsigned short lb = __builtin_bit_cast(unsigned short, __float2bfloat16(av[j] - hi));
                vh[j] = (short)hb; vl[j] = (short)lb;
            }
            *(short8*)&AsHi[arow][akoff] = vh;
            *(short8*)&AsLo[arow][akoff] = vl;
        }
        *(short8*)&Ws[arow][akoff] = *(const short8*)(WT + (size_t)(bn + arow) * K + k0 + akoff);
        __syncthreads();
#pragma unroll
        for (int i = 0; i < 2; ++i) {
            short8 ah = *(const short8*)&AsHi[wm + i*16 + l15][quad * 8];
            short8 al = *(const short8*)&AsLo[wm + i*16 + l15][quad * 8];
#pragma unroll
            for (int j = 0; j < 2; ++j) {
                short8 b = *(const short8*)&Ws[wn + j*16 + l15][quad * 8];
                acc[i][j] = __builtin_amdgcn_mfma_f32_16x16x32_bf16(ah, b, acc[i][j], 0, 0, 0);
                acc[i][j] = __builtin_amdgcn_mfma_f32_16x16x32_bf16(al, b, acc[i][j], 0, 0, 0);
            }
        }
        __syncthreads();
    }

#pragma unroll
    for (int i = 0; i < 2; ++i)
#pragma unroll
    for (int j = 0; j < 2; ++j) {
        int n = bn + wn + j*16 + l15;
        float bv = f32w ? ((const float*)bias)[n]
                        : __bfloat162float(((const bf16*)bias)[n]);
#pragma unroll
        for (int r = 0; r < 4; ++r) {
            int m = bm + wm + i*16 + quad*4 + r;
            C[(size_t)m * THREE_U + n] = acc[i][j][r] + bv;
        }
    }
}

// ---------------- weight-stationary GRU recurrence ----------------
// GBLKS blocks/group (x2 for biGRU), 384 thr. Block g owns units [g*32,+32);
// wave w: gate=w>>1, half=w&1, holds 512x16 U-slice as 16 B-frags.
// y written f32; h-exchange bf16 double buffer + epoch-flag barrier.
__global__ __launch_bounds__(384) void gru_mfma(
    const float* __restrict__ xp0, const void* __restrict__ U0, const void* __restrict__ b0full,
    const float* __restrict__ xp1, const void* __restrict__ U1, const void* __restrict__ b1full,
    const void* __restrict__ x,
    float* __restrict__ ybuf, int y_stride,
    void* __restrict__ outv,
    uint16_t* __restrict__ hbase,
    int* __restrict__ bar, int flag_base,
    const int* __restrict__ flags)
{
    const bool f32w = flags[0] != 0;
    const bool i64  = flags[1] != 0;

    int group = 0, gblk = blockIdx.x;
    const float* xp = xp0; const void* U = U0; const void* bfull = b0full;
    bool bwd = false; int coloff = 0;
    if (xp1 != nullptr) {
        group = blockIdx.x >> 4; gblk = blockIdx.x & 15;
        if (group == 1) { bwd = true; xp = xp1; U = U1; bfull = b1full; coloff = UNITS; }
    }
    int* flag = bar + flag_base + group * GBLKS;
    uint16_t* hpair = hbase + group * 2 * (NB * UNITS);

    const int tid  = threadIdx.x;
    const int wave = tid >> 6;
    const int lane = tid & 63;
    const int quad = lane >> 4;
    const int ncol = lane & 15;
    const int gate_w = wave >> 1;   // 0=z 1=r 2=hh
    const int hf     = wave & 1;

    __shared__ float gatesLDS[3][NB][32];
    __shared__ float hsLDS[NB][32];
    __shared__ float biasLDS[3][32];
    __shared__ int   maskLDS[NB];

    for (int p = tid; p < NB*32; p += 384) hsLDS[p >> 5][p & 31] = 0.f;
    if (tid < 96) {
        int g = tid >> 5, u = tid & 31;
        int idx = THREE_U + g*UNITS + gblk*32 + u;   // b_rec row
        biasLDS[g][u] = f32w ? ((const float*)bfull)[idx]
                             : __bfloat162float(((const bf16*)bfull)[idx]);
    }

    // Register-resident B-frags: B[k = kk*32+quad*8+j][n = ncol]
    short8 Bf[16];
    {
        const int col = gate_w*UNITS + gblk*32 + hf*16 + ncol;
#pragma unroll
        for (int kk = 0; kk < 16; ++kk) {
            short8 v;
#pragma unroll
            for (int j = 0; j < 8; ++j) {
                int k = kk*32 + quad*8 + j;
                unsigned short bits;
                if (f32w) {
                    bits = __builtin_bit_cast(unsigned short,
                        __float2bfloat16(((const float*)U)[(size_t)k*THREE_U + col]));
                } else {
                    bits = ((const uint16_t*)U)[(size_t)k*THREE_U + col];
                }
                v[j] = (short)bits;
            }
            Bf[kk] = v;
        }
    }
    __syncthreads();

    for (int ts = 0; ts < T_SEQ; ++ts) {
        const int t = bwd ? (T_SEQ-1-ts) : ts;
        const uint16_t* hc = hpair + (ts & 1) * (NB*UNITS);
        uint16_t* hnx      = hpair + ((ts+1) & 1) * (NB*UNITS);

        // (1) prefetch mask + xp for this thread's epilogue pairs
        if (tid < NB) maskLDS[tid] = (tok_at(x, tid*T_SEQ + t, i64) != 0);
        float pxz[3], pxr[3], pxh[3];
#pragma unroll
        for (int c = 0; c < 3; ++c) {
            int p = tid + c*384;
            if (p < NB*32) {
                int b = p >> 5, u = p & 31;
                const float* xpt = xp + ((size_t)b*T_SEQ + t)*THREE_U + gblk*32 + u;
                pxz[c] = xpt[0]; pxr[c] = xpt[UNITS]; pxh[c] = xpt[2*UNITS];
            }
        }

        // (2) rec = h[32,512] @ Uslice[512,16]
        f32x4 acc0 = {0.f,0.f,0.f,0.f};
        f32x4 acc1 = {0.f,0.f,0.f,0.f};
        {
            const uint16_t* base0 = hc + (size_t)ncol*UNITS + quad*8;  // b 0..15
            const uint16_t* base1 = base0 + 16*UNITS;                   // b 16..31
#pragma unroll
            for (int kk = 0; kk < 16; ++kk) {
                short8 a0 = *(const short8*)(base0 + kk*32);
                short8 a1 = *(const short8*)(base1 + kk*32);
                acc0 = __builtin_amdgcn_mfma_f32_16x16x32_bf16(a0, Bf[kk], acc0, 0, 0, 0);
                acc1 = __builtin_amdgcn_mfma_f32_16x16x32_bf16(a1, Bf[kk], acc1, 0, 0, 0);
            }
        }
        // (3) gates -> LDS (C/D: col=lane&15, row=quad*4+reg)
        {
            const int u = hf*16 + ncol;
#pragma unroll
            for (int r = 0; r < 4; ++r) {
                gatesLDS[gate_w][quad*4 + r][u]      = acc0[r];
                gatesLDS[gate_w][16 + quad*4 + r][u] = acc1[r];
            }
        }
        __syncthreads();   // (4)

        // (5) epilogue
#pragma unroll
        for (int c = 0; c < 3; ++c) {
            int p = tid + c*384;
            if (p < NB*32) {
                const int b = p >> 5, u = p & 31;
                const int ug = gblk*32 + u;
                const float hprev = hsLDS[b][u];
                const float rz = gatesLDS[0][b][u] + biasLDS[0][u];
                const float rr = gatesLDS[1][b][u] + biasLDS[1][u];
                const float rh = gatesLDS[2][b][u] + biasLDS[2][u];
                const float z = sigf(pxz[c] + rz);
                const float r = sigf(pxr[c] + rr);
                const float g = sigf(pxh[c] + r*rh);
                float hn = z*hprev + (1.f - z)*g;
                if (!maskLDS[b]) hn = hprev;
                hsLDS[b][u] = hn;
                const unsigned short h16 =
                    __builtin_bit_cast(unsigned short, __float2bfloat16(hn));
                hnx[b*UNITS + ug] = h16;
                if (outv) {
                    const size_t o = ((size_t)b*T_SEQ + t)*UNITS + ug;
                    if (f32w) {
                        ((float*)outv)[o] = hn;
                        if (ts == T_SEQ-1)
                            ((float*)outv)[(size_t)NB*T_SEQ*UNITS + (size_t)b*UNITS + ug] = hn;
                    } else {
                        ((uint16_t*)outv)[o] = h16;
                        if (ts == T_SEQ-1)
                            ((uint16_t*)outv)[(size_t)NB*T_SEQ*UNITS + (size_t)b*UNITS + ug] = h16;
                    }
                } else {
                    ybuf[((size_t)b*T_SEQ + t)*y_stride + coloff + ug] = hn;
                }
            }
        }
        __syncthreads();   // (6) all epilogue stores vmcnt-drained

        // (7) inter-block epoch barrier
        if (ts < T_SEQ-1) {
            const int target = ts + 1;
            if (tid == 0) {
                __threadfence();   // agent release fence: writeback h stores
                __hip_atomic_store(flag + gblk, target, __ATOMIC_RELEASE,
                                   __HIP_MEMORY_SCOPE_AGENT);
            }
            if (tid < GBLKS) {
                int spins = 0;
                while (__hip_atomic_load(flag + tid, __ATOMIC_RELAXED,
                                         __HIP_MEMORY_SCOPE_AGENT) < target) {
                    __builtin_amdgcn_s_sleep(1);
                    if ((++spins & 31) == 0) {
                        (void)__hip_atomic_load(flag + tid, __ATOMIC_ACQUIRE,
                                                __HIP_MEMORY_SCOPE_AGENT);
                    }
                }
            }
            if (tid == 0) __threadfence();   // acquire: inv stale L1/L2 once
            __syncthreads();   // (8)
        }
    }
}

extern "C" void kernel_launch(void* const* d_in, const int* in_sizes, int n_in,
                              void* d_out, int out_size, void* d_ws, size_t ws_size,
                              hipStream_t stream) {
    const void* x     = d_in[0];
    const void* E     = d_in[2];
    const void* W_fw  = d_in[3];
    const void* U_fw  = d_in[4];
    const void* b_fw  = d_in[5];
    const void* W_bw  = d_in[6];
    const void* U_bw  = d_in[7];
    const void* b_bw  = d_in[8];
    const void* W_m0  = d_in[9];
    const void* U_m0  = d_in[10];
    const void* b_m0  = d_in[11];
    const void* W_m1  = d_in[12];
    const void* U_m1  = d_in[13];
    const void* b_m1  = d_in[14];
    const void* W_top = d_in[15];
    const void* U_top = d_in[16];
    const void* b_top = d_in[17];

    float* ws = (float*)d_ws;
    float*    XPA = ws + OFF_XPA;                    // 4096x1536 f32
    float*    XPB = ws + OFF_XPB;                    // 4096x1536 f32 (bw xp)
    float*    Y1  = XPB;                             // 4096x512 f32 (post-bi)
    float*    Y2  = XPB + 2097152;                   // 4096x512 f32
    uint16_t* WTL = (uint16_t*)(XPB + 4194304);      // late WT (<=1536x1024 bf16)
    float*    YBI = ws + OFF_YBI;                    // 4096x1024 f32 concat
    uint16_t* WTE = (uint16_t*)YBI;                  // early WT (fw,bw) alias
    uint16_t* WTEb = WTE + 786432;                   // bw at +1536*512 bf16
    int*      flags = (int*)(ws + OFF_FLG);
    int*      bar   = (int*)(ws + OFF_BAR);
    uint16_t* hb    = (uint16_t*)(ws + OFF_H);

    // zero flags + barrier slots + h pairs
    hipMemsetAsync((char*)d_ws + (size_t)OFF_FLG*4, 0,
                   (size_t)(OFF_END - OFF_FLG)*4, stream);
    detect_dtypes<<<1, 64, 0, stream>>>(U_fw, x, flags);

    const dim3 b256(256);
    const dim3 gT512(16, 48), gT1024(32, 48);
    const dim3 gG2(24, 64, 2), gG1(24, 64, 1);

    // --- biGRU --- (early WT lives in YBI; dead before gru-bi writes YBI)
    transpose_w<<<gT512, b256, 0, stream>>>(W_fw, WTE, 512, flags);
    transpose_w<<<gT512, b256, 0, stream>>>(W_bw, WTEb, 512, flags);
    gemm_mfma<<<gG2, b256, 0, stream>>>(nullptr, 0, x, E,
                                        WTE, b_fw, XPA,
                                        WTEb, b_bw, XPB, 512, flags);
    gru_mfma<<<32, 384, 0, stream>>>(XPA, U_fw, b_fw,
                                     XPB, U_bw, b_bw,
                                     x, YBI, 1024, nullptr, hb, bar, 0, flags);
    // --- m0 (K=1024): WT -> WTL (XPB late region; bw xp dead) ---
    transpose_w<<<gT1024, b256, 0, stream>>>(W_m0, WTL, 1024, flags);
    gemm_mfma<<<gG1, b256, 0, stream>>>(YBI, 1024, nullptr, nullptr,
                                        WTL, b_m0, XPA,
                                        nullptr, nullptr, nullptr, 1024, flags);
    hipMemsetAsync(hb, 0, 2*NB*UNITS*2, stream);
    gru_mfma<<<16, 384, 0, stream>>>(XPA, U_m0, b_m0,
                                     nullptr, nullptr, nullptr,
                                     x, Y1, 512, nullptr, hb, bar, 32, flags);
    // --- m1 ---
    transpose_w<<<gT512, b256, 0, stream>>>(W_m1, WTL, 512, flags);
    gemm_mfma<<<gG1, b256, 0, stream>>>(Y1, 512, nullptr, nullptr,
                                        WTL, b_m1, XPA,
                                        nullptr, nullptr, nullptr, 512, flags);
    hipMemsetAsync(hb, 0, 2*NB*UNITS*2, stream);
    gru_mfma<<<16, 384, 0, stream>>>(XPA, U_m1, b_m1,
                                     nullptr, nullptr, nullptr,
                                     x, Y2, 512, nullptr, hb, bar, 48, flags);
    // --- top ---
    transpose_w<<<gT512, b256, 0, stream>>>(W_top, WTL, 512, flags);
    gemm_mfma<<<gG1, b256, 0, stream>>>(Y2, 512, nullptr, nullptr,
                                        WTL, b_top, XPA,
                                        nullptr, nullptr, nullptr, 512, flags);
    hipMemsetAsync(hb, 0, 2*NB*UNITS*2, stream);
    gru_mfma<<<16, 384, 0, stream>>>(XPA, U_top, b_top,
                                     nullptr, nullptr, nullptr,
                                     x, nullptr, 0, d_out, hb, bar, 64, flags);
}